// Round 1
// baseline (13189.188 us; speedup 1.0000x reference)
//
#include <hip/hip_runtime.h>
#include <math.h>

#define P_TOK 4096
#define T_TOK 1024
#define KV_TOK 5120
#define DIM 2048
#define VOCAB 32000
#define NHEAD 8
#define DHEAD 256
#define FFDIM 8192
#define NLAYER 2

using f32x4  = __attribute__((ext_vector_type(4))) float;
using bf16x4 = __attribute__((ext_vector_type(4))) __bf16;
using bf16x8 = __attribute__((ext_vector_type(8))) __bf16;

// ---------------------------------------------------------------------------
// GEMM: C[M,N] = A[M,K] @ B, fp32 in/out, bf16 MFMA accumulate fp32.
// BT=true : B is [N,K] row-major (ldb = row stride)  -> direct staging
// BT=false: B is [K,N] row-major                      -> transpose-on-stage
// Tile 64x64x32, 4 waves (2x2), each wave 2x2 fragments of 16x16x32.
// Requires M%64==0, N%64==0, K%32==0 (all shapes here satisfy this).
// ---------------------------------------------------------------------------
template<bool BT>
__global__ __launch_bounds__(256) void gemm_kernel(
    const float* __restrict__ A, const float* __restrict__ B, float* __restrict__ C,
    int M, int N, int K, int lda, int ldb, int ldc)
{
  __shared__ __align__(16) __bf16 As[64][40];   // [m][k], +8 pad
  __shared__ __align__(16) __bf16 Bs[64][40];   // [n][k], +8 pad
  const int tid = threadIdx.x;
  const int bm = blockIdx.y << 6;
  const int bn = blockIdx.x << 6;
  const int lane = tid & 63;
  const int wave = tid >> 6;
  const int wm = (wave >> 1) << 5;
  const int wn = (wave & 1) << 5;
  const int fr = lane & 15;     // fragment row/col within 16
  const int fq = lane >> 4;     // k-group 0..3
  f32x4 acc[2][2] = {};
  const int ar  = tid >> 3;          // 0..31 (row for A/BT staging)
  const int ak  = (tid & 7) << 2;    // 0,4,..,28 (k col)
  const int bkr = tid >> 4;          // 0..15 (k row for !BT staging)
  const int bnc = (tid & 15) << 2;   // 0,4,..,60 (n col)

  for (int k0 = 0; k0 < K; k0 += 32) {
#pragma unroll
    for (int p = 0; p < 2; ++p) {
      const int row = ar + (p << 5);
      const float4 v = *reinterpret_cast<const float4*>(A + (size_t)(bm + row) * lda + (k0 + ak));
      bf16x4 h; h[0] = (__bf16)v.x; h[1] = (__bf16)v.y; h[2] = (__bf16)v.z; h[3] = (__bf16)v.w;
      *reinterpret_cast<bf16x4*>(&As[row][ak]) = h;
    }
    if (BT) {
#pragma unroll
      for (int p = 0; p < 2; ++p) {
        const int row = ar + (p << 5);
        const float4 v = *reinterpret_cast<const float4*>(B + (size_t)(bn + row) * ldb + (k0 + ak));
        bf16x4 h; h[0] = (__bf16)v.x; h[1] = (__bf16)v.y; h[2] = (__bf16)v.z; h[3] = (__bf16)v.w;
        *reinterpret_cast<bf16x4*>(&Bs[row][ak]) = h;
      }
    } else {
#pragma unroll
      for (int p = 0; p < 2; ++p) {
        const int kk = bkr + (p << 4);
        const float4 v = *reinterpret_cast<const float4*>(B + (size_t)(k0 + kk) * ldb + (bn + bnc));
        Bs[bnc + 0][kk] = (__bf16)v.x;
        Bs[bnc + 1][kk] = (__bf16)v.y;
        Bs[bnc + 2][kk] = (__bf16)v.z;
        Bs[bnc + 3][kk] = (__bf16)v.w;
      }
    }
    __syncthreads();
    const bf16x8 a0 = *reinterpret_cast<const bf16x8*>(&As[wm + fr][fq << 3]);
    const bf16x8 a1 = *reinterpret_cast<const bf16x8*>(&As[wm + 16 + fr][fq << 3]);
    const bf16x8 b0 = *reinterpret_cast<const bf16x8*>(&Bs[wn + fr][fq << 3]);
    const bf16x8 b1 = *reinterpret_cast<const bf16x8*>(&Bs[wn + 16 + fr][fq << 3]);
    acc[0][0] = __builtin_amdgcn_mfma_f32_16x16x32_bf16(a0, b0, acc[0][0], 0, 0, 0);
    acc[0][1] = __builtin_amdgcn_mfma_f32_16x16x32_bf16(a0, b1, acc[0][1], 0, 0, 0);
    acc[1][0] = __builtin_amdgcn_mfma_f32_16x16x32_bf16(a1, b0, acc[1][0], 0, 0, 0);
    acc[1][1] = __builtin_amdgcn_mfma_f32_16x16x32_bf16(a1, b1, acc[1][1], 0, 0, 0);
    __syncthreads();
  }
#pragma unroll
  for (int mi = 0; mi < 2; ++mi)
#pragma unroll
    for (int ni = 0; ni < 2; ++ni)
#pragma unroll
      for (int r = 0; r < 4; ++r)
        C[(size_t)(bm + wm + mi * 16 + fq * 4 + r) * ldc + (bn + wn + ni * 16 + fr)] = acc[mi][ni][r];
}

// ---------------------------------------------------------------------------
// RMSNorm (D=2048 fixed): one block per row; optional source-row gather.
// ---------------------------------------------------------------------------
__global__ __launch_bounds__(256) void rms_kernel(const float* __restrict__ x,
    const float* __restrict__ g, float* __restrict__ y, const int* __restrict__ row_idx)
{
  __shared__ float red[256];
  const int r = blockIdx.x;
  const int src = row_idx ? row_idx[r] : r;
  const float* xr = x + (size_t)src * DIM;
  float* yr = y + (size_t)r * DIM;
  const int t = threadIdx.x;
  const float4 v0 = *reinterpret_cast<const float4*>(xr + t * 4);
  const float4 v1 = *reinterpret_cast<const float4*>(xr + 1024 + t * 4);
  float ss = v0.x * v0.x + v0.y * v0.y + v0.z * v0.z + v0.w * v0.w
           + v1.x * v1.x + v1.y * v1.y + v1.z * v1.z + v1.w * v1.w;
  red[t] = ss; __syncthreads();
  for (int s = 128; s > 0; s >>= 1) { if (t < s) red[t] += red[t + s]; __syncthreads(); }
  const float inv = rsqrtf(red[0] * (1.0f / DIM) + 1e-6f);
  const float4 g0 = *reinterpret_cast<const float4*>(g + t * 4);
  const float4 g1 = *reinterpret_cast<const float4*>(g + 1024 + t * 4);
  float4 o0, o1;
  o0.x = v0.x * g0.x * inv; o0.y = v0.y * g0.y * inv; o0.z = v0.z * g0.z * inv; o0.w = v0.w * g0.w * inv;
  o1.x = v1.x * g1.x * inv; o1.y = v1.y * g1.y * inv; o1.z = v1.z * g1.z * inv; o1.w = v1.w * g1.w * inv;
  *reinterpret_cast<float4*>(yr + t * 4) = o0;
  *reinterpret_cast<float4*>(yr + 1024 + t * 4) = o1;
}

// ---------------------------------------------------------------------------
// Embedding / row gather (D=2048)
// ---------------------------------------------------------------------------
__global__ __launch_bounds__(256) void gather_rows_kernel(const float* __restrict__ tab,
    const int* __restrict__ ids, float* __restrict__ out)
{
  const int r = blockIdx.x;
  const float* src = tab + (size_t)ids[r] * DIM;
  float* dst = out + (size_t)r * DIM;
  const int t = threadIdx.x;
  *reinterpret_cast<float4*>(dst + t * 4) = *reinterpret_cast<const float4*>(src + t * 4);
  *reinterpret_cast<float4*>(dst + 1024 + t * 4) = *reinterpret_cast<const float4*>(src + 1024 + t * 4);
}

__global__ __launch_bounds__(256) void add_kernel(const float* __restrict__ a,
    const float* __restrict__ b, float* __restrict__ o, int n4)
{
  const int i = blockIdx.x * 256 + threadIdx.x;
  if (i >= n4) return;
  const float4 x = reinterpret_cast<const float4*>(a)[i];
  const float4 y = reinterpret_cast<const float4*>(b)[i];
  float4 z; z.x = x.x + y.x; z.y = x.y + y.y; z.z = x.z + y.z; z.w = x.w + y.w;
  reinterpret_cast<float4*>(o)[i] = z;
}

__device__ __forceinline__ float gelu_tanh(float u) {
  const float c = 0.7978845608028654f * (u + 0.044715f * u * u * u);
  return 0.5f * u * (1.0f + tanhf(c));
}

__global__ __launch_bounds__(256) void gelu_kernel(float* __restrict__ x, int n4)
{
  const int i = blockIdx.x * 256 + threadIdx.x;
  if (i >= n4) return;
  float4 v = reinterpret_cast<float4*>(x)[i];
  v.x = gelu_tanh(v.x); v.y = gelu_tanh(v.y); v.z = gelu_tanh(v.z); v.w = gelu_tanh(v.w);
  reinterpret_cast<float4*>(x)[i] = v;
}

// ---------------------------------------------------------------------------
// Masked softmax over score rows, mask generated on the fly.
// MODE 0: target prefill, rows=P cols=P: vis = pb[q]==pb[k] && pp[q]>=pp[k]
// MODE 1: draft, rows=T cols=P+T:
//   k <  P: vis = pb[k]==tb[q] && anchor(q) > pp[k]
//   k >= P: vis = tb[k-P]==tb[q] && (q/16)==((k-P)/16)
// val = vis ? s/16 : -1e30, then softmax (matches reference exactly).
// ---------------------------------------------------------------------------
template<int MODE>
__global__ __launch_bounds__(256) void attn_softmax_kernel(float* __restrict__ S, int cols,
    const int* __restrict__ pb, const int* __restrict__ pp,
    const int* __restrict__ tb, const int* __restrict__ tp)
{
  extern __shared__ float row[];
  __shared__ float red[256];
  const int q = blockIdx.x;
  const int t = threadIdx.x;
  float* Sr = S + (size_t)q * cols;
  int qb, qp = 0, anchor = 0;
  if (MODE == 0) { qb = pb[q]; qp = pp[q]; }
  else           { qb = tb[q]; anchor = tp[(q >> 4) << 4]; }
  float m = -3.0e38f;
  for (int k = t; k < cols; k += 256) {
    bool vis;
    if (MODE == 0) {
      vis = (pb[k] == qb) && (qp >= pp[k]);
    } else {
      if (k < P_TOK) vis = (pb[k] == qb) && (anchor > pp[k]);
      else { const int kk = k - P_TOK; vis = (tb[kk] == qb) && ((q >> 4) == (kk >> 4)); }
    }
    const float val = vis ? Sr[k] * 0.0625f : -1.0e30f;
    row[k] = val;
    m = fmaxf(m, val);
  }
  red[t] = m; __syncthreads();
  for (int s = 128; s > 0; s >>= 1) { if (t < s) red[t] = fmaxf(red[t], red[t + s]); __syncthreads(); }
  m = red[0]; __syncthreads();
  float sum = 0.f;
  for (int k = t; k < cols; k += 256) { const float e = expf(row[k] - m); row[k] = e; sum += e; }
  red[t] = sum; __syncthreads();
  for (int s = 128; s > 0; s >>= 1) { if (t < s) red[t] += red[t + s]; __syncthreads(); }
  const float inv = 1.0f / red[0];
  for (int k = t; k < cols; k += 256) Sr[k] = row[k] * inv;
}

// ---------------------------------------------------------------------------
// KD loss: forward KL(teacher || student) per row, masked, / num_items.
// ---------------------------------------------------------------------------
__device__ __forceinline__ float block_sum(float v, float* red) {
  const int t = threadIdx.x;
  __syncthreads();
  red[t] = v; __syncthreads();
  for (int s = 128; s > 0; s >>= 1) { if (t < s) red[t] += red[t + s]; __syncthreads(); }
  return red[0];
}
__device__ __forceinline__ float block_max(float v, float* red) {
  const int t = threadIdx.x;
  __syncthreads();
  red[t] = v; __syncthreads();
  for (int s = 128; s > 0; s >>= 1) { if (t < s) red[t] = fmaxf(red[t], red[t + s]); __syncthreads(); }
  return red[0];
}

__global__ __launch_bounds__(256) void kl_loss_kernel(const float* __restrict__ TL,
    const float* __restrict__ SL, const int* __restrict__ labels,
    const int* __restrict__ nitems, float* __restrict__ out)
{
  __shared__ float red[256];
  const int rowi = blockIdx.x;
  if (labels[rowi] == -100) return;
  const float* tl = TL + (size_t)rowi * VOCAB;
  const float* sl = SL + (size_t)rowi * VOCAB;
  const int t = threadIdx.x;
  float mt = -3.0e38f, ms = -3.0e38f;
  for (int v = t; v < VOCAB; v += 256) { mt = fmaxf(mt, tl[v]); ms = fmaxf(ms, sl[v]); }
  mt = block_max(mt, red);
  ms = block_max(ms, red);
  float st = 0.f, ssm = 0.f;
  for (int v = t; v < VOCAB; v += 256) { st += expf(tl[v] - mt); ssm += expf(sl[v] - ms); }
  st  = block_sum(st, red);
  ssm = block_sum(ssm, red);
  const float lset = mt + logf(st);
  const float lses = ms + logf(ssm);
  float kl = 0.f;
  for (int v = t; v < VOCAB; v += 256) {
    const float lpt = tl[v] - lset;
    kl += expf(lpt) * (lpt - (sl[v] - lses));
  }
  kl = block_sum(kl, red);
  if (t == 0) {
    const int raw = nitems[0];
    // python int -> int32/int64 (low word = value); python float -> f32 bits
    const float n = (raw > 0 && raw < 1000000) ? (float)raw : __int_as_float(raw);
    atomicAdd(out, kl / n);
  }
}

// ---------------------------------------------------------------------------
static inline void launch_gemm(bool bt, const float* A, const float* B, float* C,
                               int M, int N, int K, int lda, int ldb, int ldc, hipStream_t s)
{
  dim3 grid(N / 64, M / 64), blk(256, 1, 1);
  if (bt) gemm_kernel<true ><<<grid, blk, 0, s>>>(A, B, C, M, N, K, lda, ldb, ldc);
  else    gemm_kernel<false><<<grid, blk, 0, s>>>(A, B, C, M, N, K, lda, ldb, ldc);
}

extern "C" void kernel_launch(void* const* d_in, const int* in_sizes, int n_in,
                              void* d_out, int out_size, void* d_ws, size_t ws_size,
                              hipStream_t stream)
{
  const int* prefix_ids = (const int*)d_in[0];
  const int* pb        = (const int*)d_in[1];
  const int* pp        = (const int*)d_in[2];
  const int* input_ids = (const int*)d_in[3];
  const int* tb        = (const int*)d_in[4];
  const int* tp        = (const int*)d_in[5];
  const int* tgi       = (const int*)d_in[6];
  const int* labels    = (const int*)d_in[7];
  const int* nitems    = (const int*)d_in[8];
  const float* Wt_embed = (const float*)d_in[9];
  const float* Wt_qkv   = (const float*)d_in[10];
  const float* Wt_o     = (const float*)d_in[11];
  const float* Wt_m1    = (const float*)d_in[12];
  const float* Wt_m2    = (const float*)d_in[13];
  const float* gt_ln1   = (const float*)d_in[14];
  const float* gt_ln2   = (const float*)d_in[15];
  const float* gt_lnf   = (const float*)d_in[16];
  const float* Wd_embed = (const float*)d_in[17];
  const float* Wd_qkv   = (const float*)d_in[18];
  const float* Wd_o     = (const float*)d_in[19];
  const float* Wd_m1    = (const float*)d_in[20];
  const float* Wd_m2    = (const float*)d_in[21];
  const float* gd_ln1   = (const float*)d_in[22];
  const float* gd_ln2   = (const float*)d_in[23];
  const float* gd_lnf   = (const float*)d_in[24];

  float* ws = (float*)d_ws;
  const size_t oX    = 0;                                   // [P,D] residual state / hidden
  const size_t oXN   = oX    + (size_t)P_TOK * DIM;         // [KV,D] rms outputs (draft: xkv_n)
  const size_t oQKV  = oXN   + (size_t)KV_TOK * DIM;        // [P,3D] / draft q+kv
  const size_t oO    = oQKV  + (size_t)P_TOK * 3 * DIM;     // [P,D] attn out
  const size_t oS    = oO    + (size_t)P_TOK * DIM;         // [P,P] scores (per head)
  const size_t oMH   = oS    + (size_t)P_TOK * P_TOK;       // [P,FF] mlp hidden
  const size_t oTN   = oMH   + (size_t)P_TOK * FFDIM;       // [T,D] normed rows scratch
  const size_t oTLOG = oTN   + (size_t)T_TOK * DIM;         // [T,V] teacher logits
  const size_t oXQ   = oTLOG + (size_t)T_TOK * VOCAB;       // [T,D] draft embeds
  const size_t oY    = oXQ   + (size_t)T_TOK * DIM;         // [T,D] draft state
  const size_t total = oY    + (size_t)T_TOK * DIM;         // ~567 MB
  if (ws_size < total * sizeof(float)) return;

  float* X    = ws + oX;
  float* XN   = ws + oXN;
  float* QKV  = ws + oQKV;
  float* O    = ws + oO;
  float* S    = ws + oS;
  float* MH   = ws + oMH;
  float* TN   = ws + oTN;
  float* TLOG = ws + oTLOG;
  float* XQ   = ws + oXQ;
  float* Y    = ws + oY;
  float* DLOG = ws + oS;   // overlay: S & MH are dead by the time DLOG is written

  hipMemsetAsync(d_out, 0, sizeof(float), stream);

  const int nD4  = P_TOK * DIM / 4, nTD4 = T_TOK * DIM / 4;

  // ---------------- target causal prefill ----------------
  gather_rows_kernel<<<P_TOK, 256, 0, stream>>>(Wt_embed, prefix_ids, X);
  for (int l = 0; l < NLAYER; ++l) {
    const float* Wqkv = Wt_qkv + (size_t)l * DIM * 3 * DIM;
    const float* Wo   = Wt_o   + (size_t)l * DIM * DIM;
    const float* Wm1  = Wt_m1  + (size_t)l * DIM * FFDIM;
    const float* Wm2  = Wt_m2  + (size_t)l * FFDIM * DIM;
    rms_kernel<<<P_TOK, 256, 0, stream>>>(X, gt_ln1 + l * DIM, XN, nullptr);
    launch_gemm(false, XN, Wqkv, QKV, P_TOK, 3 * DIM, DIM, DIM, 3 * DIM, 3 * DIM, stream);
    for (int h = 0; h < NHEAD; ++h) {
      const float* Qh = QKV + h * DHEAD;
      const float* Kh = QKV + DIM + h * DHEAD;
      const float* Vh = QKV + 2 * DIM + h * DHEAD;
      launch_gemm(true, Qh, Kh, S, P_TOK, P_TOK, DHEAD, 3 * DIM, 3 * DIM, P_TOK, stream);
      attn_softmax_kernel<0><<<P_TOK, 256, P_TOK * 4, stream>>>(S, P_TOK, pb, pp, nullptr, nullptr);
      launch_gemm(false, S, Vh, O + h * DHEAD, P_TOK, DHEAD, P_TOK, P_TOK, 3 * DIM, DIM, stream);
    }
    launch_gemm(false, O, Wo, XN, P_TOK, DIM, DIM, DIM, DIM, DIM, stream);
    add_kernel<<<(nD4 + 255) / 256, 256, 0, stream>>>(X, XN, X, nD4);
    rms_kernel<<<P_TOK, 256, 0, stream>>>(X, gt_ln2 + l * DIM, XN, nullptr);
    launch_gemm(false, XN, Wm1, MH, P_TOK, FFDIM, DIM, DIM, FFDIM, FFDIM, stream);
    gelu_kernel<<<(P_TOK * FFDIM / 4 + 255) / 256, 256, 0, stream>>>(MH, P_TOK * FFDIM / 4);
    launch_gemm(false, MH, Wm2, XN, P_TOK, DIM, FFDIM, FFDIM, DIM, DIM, stream);
    add_kernel<<<(nD4 + 255) / 256, 256, 0, stream>>>(X, XN, X, nD4);
  }

  // ---------------- teacher logits (gathered rows only) ----------------
  rms_kernel<<<T_TOK, 256, 0, stream>>>(X, gt_lnf, TN, tgi);
  launch_gemm(true, TN, Wt_embed, TLOG, T_TOK, VOCAB, DIM, DIM, DIM, VOCAB, stream);

  // ---------------- draft forward ----------------
  gather_rows_kernel<<<T_TOK, 256, 0, stream>>>(Wd_embed, input_ids, XQ);
  rms_kernel<<<P_TOK, 256, 0, stream>>>(X, gd_ln1, XN, nullptr);                       // xkv_n[0:P]
  rms_kernel<<<T_TOK, 256, 0, stream>>>(XQ, gd_ln1, XN + (size_t)P_TOK * DIM, nullptr); // xkv_n[P:]
  float* Qd  = QKV;                         // [T, D]
  float* KVd = QKV + (size_t)T_TOK * DIM;   // [KV, 2D] (k | v)
  launch_gemm(false, XN + (size_t)P_TOK * DIM, Wd_qkv, Qd, T_TOK, DIM, DIM, DIM, 3 * DIM, DIM, stream);
  launch_gemm(false, XN, Wd_qkv + DIM, KVd, KV_TOK, 2 * DIM, DIM, DIM, 3 * DIM, 2 * DIM, stream);
  for (int h = 0; h < NHEAD; ++h) {
    const float* Qh = Qd + h * DHEAD;
    const float* Kh = KVd + h * DHEAD;
    const float* Vh = KVd + DIM + h * DHEAD;
    launch_gemm(true, Qh, Kh, S, T_TOK, KV_TOK, DHEAD, DIM, 2 * DIM, KV_TOK, stream);
    attn_softmax_kernel<1><<<T_TOK, 256, KV_TOK * 4, stream>>>(S, KV_TOK, pb, pp, tb, tp);
    launch_gemm(false, S, Vh, O + h * DHEAD, T_TOK, DHEAD, KV_TOK, KV_TOK, 2 * DIM, DIM, stream);
  }
  launch_gemm(false, O, Wd_o, TN, T_TOK, DIM, DIM, DIM, DIM, DIM, stream);
  add_kernel<<<(nTD4 + 255) / 256, 256, 0, stream>>>(XQ, TN, Y, nTD4);
  rms_kernel<<<T_TOK, 256, 0, stream>>>(Y, gd_ln2, TN, nullptr);
  launch_gemm(false, TN, Wd_m1, MH, T_TOK, FFDIM, DIM, DIM, FFDIM, FFDIM, stream);
  gelu_kernel<<<(T_TOK * FFDIM / 4 + 255) / 256, 256, 0, stream>>>(MH, T_TOK * FFDIM / 4);
  launch_gemm(false, MH, Wd_m2, TN, T_TOK, DIM, FFDIM, FFDIM, DIM, DIM, stream);
  add_kernel<<<(nTD4 + 255) / 256, 256, 0, stream>>>(Y, TN, Y, nTD4);
  rms_kernel<<<T_TOK, 256, 0, stream>>>(Y, gd_lnf, TN, nullptr);
  launch_gemm(true, TN, Wd_embed, DLOG, T_TOK, VOCAB, DIM, DIM, DIM, VOCAB, stream);

  // ---------------- KD loss ----------------
  kl_loss_kernel<<<T_TOK, 256, 0, stream>>>(TLOG, DLOG, labels, nitems, (float*)d_out);
}

// Round 2
// 6083.684 us; speedup vs baseline: 2.1680x; 2.1680x over previous
//
#include <hip/hip_runtime.h>
#include <math.h>

#define P_TOK 4096
#define T_TOK 1024
#define KV_TOK 5120
#define DIM 2048
#define VOCAB 32000
#define NHEAD 8
#define DHEAD 256
#define FFDIM 8192
#define NLAYER 2

using f32x4  = __attribute__((ext_vector_type(4))) float;
using bf16x4 = __attribute__((ext_vector_type(4))) __bf16;
using bf16x8 = __attribute__((ext_vector_type(8))) __bf16;

typedef const __attribute__((address_space(1))) void* gp1_t;
typedef __attribute__((address_space(3))) void* lp3_t;

__device__ __forceinline__ void gload16(const void* g, void* l) {
  __builtin_amdgcn_global_load_lds((gp1_t)g, (lp3_t)l, 16, 0, 0);
}

// ---------------------------------------------------------------------------
// GEMM (m97 structure): C[M,N] = A[M,K] @ B^T, A bf16 [M,K] lda, B bf16 [N,K] ldb.
// 128x128 tile, BK=64, 4 waves (2x2), 4x4 16x16x32 frags/wave, global_load_lds.
// Requires M%128==0, N%128==0, K%64==0, 16B-aligned base/lda/ldb/k offsets.
// CT: float or __bf16 output; ACCUM: C += (fp32 residual fusion).
// ---------------------------------------------------------------------------
template<typename CT, bool ACCUM>
__global__ __launch_bounds__(256) void gemm_bt(
    const __bf16* __restrict__ A, const __bf16* __restrict__ B, CT* __restrict__ C,
    int M, int N, int K, int lda, int ldb, int ldc)
{
  __shared__ __align__(16) __bf16 As[128][64];   // 16 KB, linear (gload_lds dest)
  __shared__ __align__(16) __bf16 Bs[128][64];   // 16 KB
  const int tid = threadIdx.x;
  const int lane = tid & 63, wave = tid >> 6;
  const int bm = blockIdx.y << 7, bn = blockIdx.x << 7;
  const int fr = lane & 15, fq = lane >> 4;
  const int wm = (wave >> 1) << 6, wn = (wave & 1) << 6;
  const int l8 = lane >> 3;            // row within 8-row chunk
  const int c8 = (lane & 7) << 3;      // col elements (16B granules)
  f32x4 acc[4][4] = {};

  for (int k0 = 0; k0 < K; k0 += 64) {
#pragma unroll
    for (int i = 0; i < 4; ++i) {
      const int c = (wave << 2) + i;       // chunk 0..15 (uniform per wave)
      const int row = (c << 3) + l8;
      gload16(A + (size_t)(bm + row) * lda + k0 + c8, (char*)(&As[0][0]) + (c << 10));
      gload16(B + (size_t)(bn + row) * ldb + k0 + c8, (char*)(&Bs[0][0]) + (c << 10));
    }
    __syncthreads();
#pragma unroll
    for (int ks = 0; ks < 2; ++ks) {
      bf16x8 a[4], b[4];
#pragma unroll
      for (int i = 0; i < 4; ++i) {
        a[i] = *reinterpret_cast<const bf16x8*>(&As[wm + (i << 4) + fr][(ks << 5) + (fq << 3)]);
        b[i] = *reinterpret_cast<const bf16x8*>(&Bs[wn + (i << 4) + fr][(ks << 5) + (fq << 3)]);
      }
#pragma unroll
      for (int mi = 0; mi < 4; ++mi)
#pragma unroll
        for (int ni = 0; ni < 4; ++ni)
          acc[mi][ni] = __builtin_amdgcn_mfma_f32_16x16x32_bf16(a[mi], b[ni], acc[mi][ni], 0, 0, 0);
    }
    __syncthreads();
  }
#pragma unroll
  for (int mi = 0; mi < 4; ++mi) {
#pragma unroll
    for (int r = 0; r < 4; ++r) {
      const size_t rowi = (size_t)(bm + wm + (mi << 4) + (fq << 2) + r);
      CT* Crow = C + rowi * ldc + bn + wn + fr;
#pragma unroll
      for (int ni = 0; ni < 4; ++ni) {
        if (ACCUM) Crow[ni << 4] += (CT)acc[mi][ni][r];
        else       Crow[ni << 4] = (CT)acc[mi][ni][r];
      }
    }
  }
}

// ---------------------------------------------------------------------------
// fp32 [R,C] (ld) -> bf16 [C,R] transpose-convert
// ---------------------------------------------------------------------------
__global__ __launch_bounds__(256) void transpose_f2b(const float* __restrict__ src,
    __bf16* __restrict__ dst, int R, int C, int ld)
{
  __shared__ float tile[32][33];
  const int bx = blockIdx.x << 5, by = blockIdx.y << 5;
  const int tx = threadIdx.x & 31, ty = threadIdx.x >> 5;
#pragma unroll
  for (int k = 0; k < 32; k += 8)
    tile[ty + k][tx] = src[(size_t)(by + ty + k) * ld + bx + tx];
  __syncthreads();
#pragma unroll
  for (int k = 0; k < 32; k += 8)
    dst[(size_t)(bx + ty + k) * R + by + tx] = (__bf16)tile[tx][ty + k];
}

// bf16 [R,C] (ld) -> bf16 [C,R]
__global__ __launch_bounds__(256) void transpose_b2b(const __bf16* __restrict__ src,
    __bf16* __restrict__ dst, int R, int C, int ld)
{
  __shared__ __bf16 tile[32][33];
  const int bx = blockIdx.x << 5, by = blockIdx.y << 5;
  const int tx = threadIdx.x & 31, ty = threadIdx.x >> 5;
#pragma unroll
  for (int k = 0; k < 32; k += 8)
    tile[ty + k][tx] = src[(size_t)(by + ty + k) * ld + bx + tx];
  __syncthreads();
#pragma unroll
  for (int k = 0; k < 32; k += 8)
    dst[(size_t)(bx + ty + k) * R + by + tx] = tile[tx][ty + k];
}

// fp32 -> bf16 elementwise (n8 = n/8)
__global__ __launch_bounds__(256) void conv_bf16(const float* __restrict__ src,
    __bf16* __restrict__ dst, long n8)
{
  const long i = (long)blockIdx.x * 256 + threadIdx.x;
  if (i >= n8) return;
  const float4 a = reinterpret_cast<const float4*>(src)[i * 2];
  const float4 b = reinterpret_cast<const float4*>(src)[i * 2 + 1];
  bf16x8 h;
  h[0] = (__bf16)a.x; h[1] = (__bf16)a.y; h[2] = (__bf16)a.z; h[3] = (__bf16)a.w;
  h[4] = (__bf16)b.x; h[5] = (__bf16)b.y; h[6] = (__bf16)b.z; h[7] = (__bf16)b.w;
  reinterpret_cast<bf16x8*>(dst)[i] = h;
}

// ---------------------------------------------------------------------------
// RMSNorm fp32 in -> bf16 out (D=2048), optional row gather
// ---------------------------------------------------------------------------
__global__ __launch_bounds__(256) void rms_bf16(const float* __restrict__ x,
    const float* __restrict__ g, __bf16* __restrict__ y, const int* __restrict__ row_idx)
{
  __shared__ float red[256];
  const int r = blockIdx.x;
  const int src = row_idx ? row_idx[r] : r;
  const float* xr = x + (size_t)src * DIM;
  __bf16* yr = y + (size_t)r * DIM;
  const int t = threadIdx.x;
  const float4 v0 = *reinterpret_cast<const float4*>(xr + t * 8);
  const float4 v1 = *reinterpret_cast<const float4*>(xr + t * 8 + 4);
  float ss = v0.x * v0.x + v0.y * v0.y + v0.z * v0.z + v0.w * v0.w
           + v1.x * v1.x + v1.y * v1.y + v1.z * v1.z + v1.w * v1.w;
  red[t] = ss; __syncthreads();
  for (int s = 128; s > 0; s >>= 1) { if (t < s) red[t] += red[t + s]; __syncthreads(); }
  const float inv = rsqrtf(red[0] * (1.0f / DIM) + 1e-6f);
  const float4 g0 = *reinterpret_cast<const float4*>(g + t * 8);
  const float4 g1 = *reinterpret_cast<const float4*>(g + t * 8 + 4);
  bf16x8 h;
  h[0] = (__bf16)(v0.x * g0.x * inv); h[1] = (__bf16)(v0.y * g0.y * inv);
  h[2] = (__bf16)(v0.z * g0.z * inv); h[3] = (__bf16)(v0.w * g0.w * inv);
  h[4] = (__bf16)(v1.x * g1.x * inv); h[5] = (__bf16)(v1.y * g1.y * inv);
  h[6] = (__bf16)(v1.z * g1.z * inv); h[7] = (__bf16)(v1.w * g1.w * inv);
  *reinterpret_cast<bf16x8*>(yr + t * 8) = h;
}

__global__ __launch_bounds__(256) void gather_rows_kernel(const float* __restrict__ tab,
    const int* __restrict__ ids, float* __restrict__ out)
{
  const int r = blockIdx.x;
  const float* src = tab + (size_t)ids[r] * DIM;
  float* dst = out + (size_t)r * DIM;
  const int t = threadIdx.x;
  *reinterpret_cast<float4*>(dst + t * 8) = *reinterpret_cast<const float4*>(src + t * 8);
  *reinterpret_cast<float4*>(dst + t * 8 + 4) = *reinterpret_cast<const float4*>(src + t * 8 + 4);
}

__device__ __forceinline__ float gelu_tanh(float u) {
  const float c = 0.7978845608028654f * (u + 0.044715f * u * u * u);
  return 0.5f * u * (1.0f + tanhf(c));
}

__global__ __launch_bounds__(256) void gelu_bf16(__bf16* __restrict__ x, long n8)
{
  const long i = (long)blockIdx.x * 256 + threadIdx.x;
  if (i >= n8) return;
  bf16x8 v = reinterpret_cast<bf16x8*>(x)[i];
#pragma unroll
  for (int j = 0; j < 8; ++j) v[j] = (__bf16)gelu_tanh((float)v[j]);
  reinterpret_cast<bf16x8*>(x)[i] = v;
}

// ---------------------------------------------------------------------------
// Masked softmax: fp32 scores row -> bf16 probs row; mask regenerated on the fly.
// ---------------------------------------------------------------------------
template<int MODE>
__global__ __launch_bounds__(256) void attn_softmax_kernel(const float* __restrict__ S,
    __bf16* __restrict__ Pout, int cols,
    const int* __restrict__ pb, const int* __restrict__ pp,
    const int* __restrict__ tb, const int* __restrict__ tp)
{
  extern __shared__ float row[];
  __shared__ float red[256];
  const int q = blockIdx.x;
  const int t = threadIdx.x;
  const float* Sr = S + (size_t)q * cols;
  __bf16* Pr = Pout + (size_t)q * cols;
  int qb, qp = 0, anchor = 0;
  if (MODE == 0) { qb = pb[q]; qp = pp[q]; }
  else           { qb = tb[q]; anchor = tp[(q >> 4) << 4]; }
  float m = -3.0e38f;
  for (int k = t; k < cols; k += 256) {
    bool vis;
    if (MODE == 0) {
      vis = (pb[k] == qb) && (qp >= pp[k]);
    } else {
      if (k < P_TOK) vis = (pb[k] == qb) && (anchor > pp[k]);
      else { const int kk = k - P_TOK; vis = (tb[kk] == qb) && ((q >> 4) == (kk >> 4)); }
    }
    const float val = vis ? Sr[k] * 0.0625f : -1.0e30f;
    row[k] = val;
    m = fmaxf(m, val);
  }
  red[t] = m; __syncthreads();
  for (int s = 128; s > 0; s >>= 1) { if (t < s) red[t] = fmaxf(red[t], red[t + s]); __syncthreads(); }
  m = red[0]; __syncthreads();
  float sum = 0.f;
  for (int k = t; k < cols; k += 256) { const float e = expf(row[k] - m); row[k] = e; sum += e; }
  red[t] = sum; __syncthreads();
  for (int s = 128; s > 0; s >>= 1) { if (t < s) red[t] += red[t + s]; __syncthreads(); }
  const float inv = 1.0f / red[0];
  for (int k = t; k < cols; k += 256) Pr[k] = (__bf16)(row[k] * inv);
}

// ---------------------------------------------------------------------------
// Teacher softmax: logits fp32 [T,V] -> PT bf16 probs, ENT[r]=sum pt*lpt, S1[r]=sum pt
// ---------------------------------------------------------------------------
__global__ __launch_bounds__(256) void teacher_softmax_kernel(const float* __restrict__ TL,
    __bf16* __restrict__ PT, float* __restrict__ ENT, float* __restrict__ S1)
{
  __shared__ float sm[256], ss[256];
  const int r = blockIdx.x, t = threadIdx.x;
  const float* tl = TL + (size_t)r * VOCAB;
  __bf16* pt = PT + (size_t)r * VOCAB;
  float m = -3.0e38f, s = 0.f;
  for (int v = t; v < VOCAB; v += 256) {
    const float x = tl[v];
    if (x > m) { s = s * expf(m - x) + 1.f; m = x; }
    else       { s += expf(x - m); }
  }
  sm[t] = m; ss[t] = s; __syncthreads();
  for (int st = 128; st > 0; st >>= 1) {
    if (t < st) {
      const float m2 = sm[t + st], s2 = ss[t + st];
      const float M = fmaxf(sm[t], m2);
      ss[t] = ss[t] * expf(sm[t] - M) + s2 * expf(m2 - M);
      sm[t] = M;
    }
    __syncthreads();
  }
  const float Mt = sm[0], Z = ss[0];
  const float invZ = 1.0f / Z, lZ = logf(Z);
  __syncthreads();
  float ent = 0.f, s1 = 0.f;
  for (int v = t; v < VOCAB; v += 256) {
    const float x = tl[v];
    const float p = expf(x - Mt) * invZ;
    const __bf16 pb_ = (__bf16)p;
    pt[v] = pb_;
    const float pf = (float)pb_;
    ent += pf * (x - Mt - lZ);
    s1 += pf;
  }
  sm[t] = ent; ss[t] = s1; __syncthreads();
  for (int st = 128; st > 0; st >>= 1) {
    if (t < st) { sm[t] += sm[t + st]; ss[t] += ss[t + st]; }
    __syncthreads();
  }
  if (t == 0) { ENT[r] = sm[0]; S1[r] = ss[0]; }
}

// ---------------------------------------------------------------------------
// KD loss: per row r (labels != -100):
//   loss_r = ENT[r] - sum_v PT*dlog + LSE(dlog)*S1[r];  atomicAdd(out, loss_r/n)
// ---------------------------------------------------------------------------
__global__ __launch_bounds__(256) void kl_loss_kernel(const float* __restrict__ DL,
    const __bf16* __restrict__ PT, const float* __restrict__ ENT, const float* __restrict__ S1,
    const int* __restrict__ labels, const int* __restrict__ nitems, float* __restrict__ out)
{
  __shared__ float sm[256], ss[256];
  const int r = blockIdx.x, t = threadIdx.x;
  if (labels[r] == -100) return;
  const float* dl = DL + (size_t)r * VOCAB;
  const __bf16* pt = PT + (size_t)r * VOCAB;
  float m = -3.0e38f, s = 0.f;
  for (int v = t; v < VOCAB; v += 256) {
    const float x = dl[v];
    if (x > m) { s = s * expf(m - x) + 1.f; m = x; }
    else       { s += expf(x - m); }
  }
  sm[t] = m; ss[t] = s; __syncthreads();
  for (int st = 128; st > 0; st >>= 1) {
    if (t < st) {
      const float m2 = sm[t + st], s2 = ss[t + st];
      const float M = fmaxf(sm[t], m2);
      ss[t] = ss[t] * expf(sm[t] - M) + s2 * expf(m2 - M);
      sm[t] = M;
    }
    __syncthreads();
  }
  const float lses = sm[0] + logf(ss[0]);
  __syncthreads();
  float cross = 0.f;
  for (int v = t; v < VOCAB; v += 256) cross += (float)pt[v] * dl[v];
  ss[t] = cross; __syncthreads();
  for (int st = 128; st > 0; st >>= 1) { if (t < st) ss[t] += ss[t + st]; __syncthreads(); }
  if (t == 0) {
    const int raw = nitems[0];
    const float n = (raw > 0 && raw < 1000000) ? (float)raw : __int_as_float(raw);
    const float loss_r = ENT[r] - ss[0] + lses * S1[r];
    atomicAdd(out, loss_r / n);
  }
}

// ---------------------------------------------------------------------------
static inline void ggemm_b(const __bf16* A, const __bf16* B, __bf16* C,
                           int M, int N, int K, int lda, int ldb, int ldc, hipStream_t s)
{ gemm_bt<__bf16, false><<<dim3(N / 128, M / 128), 256, 0, s>>>(A, B, C, M, N, K, lda, ldb, ldc); }
static inline void ggemm_f(const __bf16* A, const __bf16* B, float* C,
                           int M, int N, int K, int lda, int ldb, int ldc, hipStream_t s)
{ gemm_bt<float, false><<<dim3(N / 128, M / 128), 256, 0, s>>>(A, B, C, M, N, K, lda, ldb, ldc); }
static inline void ggemm_acc(const __bf16* A, const __bf16* B, float* C,
                             int M, int N, int K, int lda, int ldb, int ldc, hipStream_t s)
{ gemm_bt<float, true><<<dim3(N / 128, M / 128), 256, 0, s>>>(A, B, C, M, N, K, lda, ldb, ldc); }

extern "C" void kernel_launch(void* const* d_in, const int* in_sizes, int n_in,
                              void* d_out, int out_size, void* d_ws, size_t ws_size,
                              hipStream_t stream)
{
  const int* prefix_ids = (const int*)d_in[0];
  const int* pb        = (const int*)d_in[1];
  const int* pp        = (const int*)d_in[2];
  const int* input_ids = (const int*)d_in[3];
  const int* tb        = (const int*)d_in[4];
  const int* tp        = (const int*)d_in[5];
  const int* tgi       = (const int*)d_in[6];
  const int* labels    = (const int*)d_in[7];
  const int* nitems    = (const int*)d_in[8];
  const float* Wt_embed = (const float*)d_in[9];
  const float* Wt_qkv   = (const float*)d_in[10];
  const float* Wt_o     = (const float*)d_in[11];
  const float* Wt_m1    = (const float*)d_in[12];
  const float* Wt_m2    = (const float*)d_in[13];
  const float* gt_ln1   = (const float*)d_in[14];
  const float* gt_ln2   = (const float*)d_in[15];
  const float* gt_lnf   = (const float*)d_in[16];
  const float* Wd_embed = (const float*)d_in[17];
  const float* Wd_qkv   = (const float*)d_in[18];
  const float* Wd_o     = (const float*)d_in[19];
  const float* Wd_m1    = (const float*)d_in[20];
  const float* Wd_m2    = (const float*)d_in[21];
  const float* gd_ln1   = (const float*)d_in[22];
  const float* gd_ln2   = (const float*)d_in[23];
  const float* gd_lnf   = (const float*)d_in[24];

  // ---------------- workspace layout (bytes) ----------------
  char* base = (char*)d_ws;
  size_t off = 0;
  auto alloc = [&](size_t bytes) { size_t o = off; off += (bytes + 255) & ~(size_t)255; return o; };
  const size_t oX    = alloc((size_t)P_TOK * DIM * 4);       // fp32 residual / hidden
  const size_t oXNb  = alloc((size_t)KV_TOK * DIM * 2);      // bf16 normed activations
  const size_t oQKVb = alloc((size_t)P_TOK * 3 * DIM * 2);   // bf16 qkv (target) / q+kv (draft)
  const size_t oOb   = alloc((size_t)P_TOK * DIM * 2);       // bf16 attn out
  const size_t oS    = alloc((size_t)P_TOK * P_TOK * 4);     // fp32 scores (target, per head)
  const size_t oPb   = alloc((size_t)P_TOK * P_TOK * 2);     // bf16 probs (target, per head)
  const size_t oVT   = alloc((size_t)DIM * KV_TOK * 2);      // bf16 V^T
  const size_t oSD   = alloc((size_t)T_TOK * KV_TOK * 4);    // fp32 draft scores (per head)
  const size_t oMHb  = alloc((size_t)P_TOK * FFDIM * 2);     // bf16 mlp hidden
  const size_t oY    = alloc((size_t)T_TOK * DIM * 4);       // fp32 draft residual
  const size_t oPT   = alloc((size_t)T_TOK * VOCAB * 2);     // bf16 teacher probs
  const size_t oENT  = alloc((size_t)T_TOK * 4);
  const size_t oS1   = alloc((size_t)T_TOK * 4);
  const size_t oWB   = alloc((size_t)(3 * DIM * DIM + DIM * DIM + DIM * FFDIM + FFDIM * DIM) * 2);
  if (ws_size < off) return;  // fail loudly (d_out stays poisoned)

  float*  X    = (float*)(base + oX);
  __bf16* XNb  = (__bf16*)(base + oXNb);
  __bf16* QKVb = (__bf16*)(base + oQKVb);
  __bf16* Ob   = (__bf16*)(base + oOb);
  float*  S    = (float*)(base + oS);
  __bf16* Pb   = (__bf16*)(base + oPb);
  __bf16* VT   = (__bf16*)(base + oVT);
  float*  SD   = (float*)(base + oSD);
  __bf16* MHb  = (__bf16*)(base + oMHb);
  float*  Y    = (float*)(base + oY);
  __bf16* PT   = (__bf16*)(base + oPT);
  float*  ENT  = (float*)(base + oENT);
  float*  S1   = (float*)(base + oS1);
  __bf16* wQkvT = (__bf16*)(base + oWB);                       // [3D, D]
  __bf16* wOT   = wQkvT + (size_t)3 * DIM * DIM;               // [D, D]
  __bf16* wM1T  = wOT + (size_t)DIM * DIM;                     // [FF, D]
  __bf16* wM2T  = wM1T + (size_t)FFDIM * DIM;                  // [D, FF]
  // overlays (temporally disjoint with their underlying regions):
  float*  TLOG = (float*)(base + oQKVb);   // teacher logits [T,V] over QKVb+Ob+S
  float*  DLOG = (float*)(base + oQKVb);   // draft  logits [T,V] over QKVb+Ob+S
  __bf16* embB = (__bf16*)(base + oPb);    // bf16 embed table over Pb+VT+SD+MHb
  __bf16* Pbd  = (__bf16*)(base + oS);     // draft probs [H,T,KV] over S+Pb

  hipMemsetAsync(d_out, 0, sizeof(float), stream);

  // ---------------- target causal prefill ----------------
  gather_rows_kernel<<<P_TOK, 256, 0, stream>>>(Wt_embed, prefix_ids, X);
  for (int l = 0; l < NLAYER; ++l) {
    transpose_f2b<<<dim3(3 * DIM / 32, DIM / 32), 256, 0, stream>>>(
        Wt_qkv + (size_t)l * DIM * 3 * DIM, wQkvT, DIM, 3 * DIM, 3 * DIM);
    transpose_f2b<<<dim3(DIM / 32, DIM / 32), 256, 0, stream>>>(
        Wt_o + (size_t)l * DIM * DIM, wOT, DIM, DIM, DIM);
    transpose_f2b<<<dim3(FFDIM / 32, DIM / 32), 256, 0, stream>>>(
        Wt_m1 + (size_t)l * DIM * FFDIM, wM1T, DIM, FFDIM, FFDIM);
    transpose_f2b<<<dim3(DIM / 32, FFDIM / 32), 256, 0, stream>>>(
        Wt_m2 + (size_t)l * FFDIM * DIM, wM2T, FFDIM, DIM, DIM);

    rms_bf16<<<P_TOK, 256, 0, stream>>>(X, gt_ln1 + l * DIM, XNb, nullptr);
    ggemm_b(XNb, wQkvT, QKVb, P_TOK, 3 * DIM, DIM, DIM, DIM, 3 * DIM, stream);
    transpose_b2b<<<dim3(DIM / 32, P_TOK / 32), 256, 0, stream>>>(
        QKVb + 2 * DIM, VT, P_TOK, DIM, 3 * DIM);                 // VT [D,P]
    for (int h = 0; h < NHEAD; ++h) {
      ggemm_f(QKVb + h * DHEAD, QKVb + DIM + h * DHEAD, S,
              P_TOK, P_TOK, DHEAD, 3 * DIM, 3 * DIM, P_TOK, stream);
      attn_softmax_kernel<0><<<P_TOK, 256, P_TOK * 4, stream>>>(S, Pb, P_TOK, pb, pp, nullptr, nullptr);
      ggemm_b(Pb, VT + (size_t)h * DHEAD * P_TOK, Ob + h * DHEAD,
              P_TOK, DHEAD, P_TOK, P_TOK, P_TOK, DIM, stream);
    }
    ggemm_acc(Ob, wOT, X, P_TOK, DIM, DIM, DIM, DIM, DIM, stream);   // X += attn@Wo
    rms_bf16<<<P_TOK, 256, 0, stream>>>(X, gt_ln2 + l * DIM, XNb, nullptr);
    ggemm_b(XNb, wM1T, MHb, P_TOK, FFDIM, DIM, DIM, DIM, FFDIM, stream);
    gelu_bf16<<<(P_TOK * FFDIM / 8 + 255) / 256, 256, 0, stream>>>(MHb, (long)P_TOK * FFDIM / 8);
    ggemm_acc(MHb, wM2T, X, P_TOK, DIM, FFDIM, FFDIM, FFDIM, DIM, stream);  // X += mlp
  }

  // ---------------- teacher logits -> PT/ENT/S1 ----------------
  rms_bf16<<<T_TOK, 256, 0, stream>>>(X, gt_lnf, XNb, tgi);
  conv_bf16<<<((long)VOCAB * DIM / 8 + 255) / 256, 256, 0, stream>>>(Wt_embed, embB, (long)VOCAB * DIM / 8);
  ggemm_f(XNb, embB, TLOG, T_TOK, VOCAB, DIM, DIM, DIM, VOCAB, stream);
  teacher_softmax_kernel<<<T_TOK, 256, 0, stream>>>(TLOG, PT, ENT, S1);

  // ---------------- draft forward ----------------
  gather_rows_kernel<<<T_TOK, 256, 0, stream>>>(Wd_embed, input_ids, Y);   // Y = xq (fp32)
  transpose_f2b<<<dim3(3 * DIM / 32, DIM / 32), 256, 0, stream>>>(Wd_qkv, wQkvT, DIM, 3 * DIM, 3 * DIM);
  transpose_f2b<<<dim3(DIM / 32, DIM / 32), 256, 0, stream>>>(Wd_o, wOT, DIM, DIM, DIM);
  transpose_f2b<<<dim3(FFDIM / 32, DIM / 32), 256, 0, stream>>>(Wd_m1, wM1T, DIM, FFDIM, FFDIM);
  transpose_f2b<<<dim3(DIM / 32, FFDIM / 32), 256, 0, stream>>>(Wd_m2, wM2T, FFDIM, DIM, DIM);

  rms_bf16<<<P_TOK, 256, 0, stream>>>(X, gd_ln1, XNb, nullptr);                     // xkv_n[0:P]
  rms_bf16<<<T_TOK, 256, 0, stream>>>(Y, gd_ln1, XNb + (size_t)P_TOK * DIM, nullptr); // xq_n
  __bf16* Qb  = QKVb;                                  // [T, D]
  __bf16* KVb = QKVb + (size_t)T_TOK * DIM;            // [KV, 2D] (k | v)
  ggemm_b(XNb + (size_t)P_TOK * DIM, wQkvT, Qb, T_TOK, DIM, DIM, DIM, DIM, DIM, stream);
  ggemm_b(XNb, wQkvT + (size_t)DIM * DIM, KVb, KV_TOK, 2 * DIM, DIM, DIM, DIM, 2 * DIM, stream);
  transpose_b2b<<<dim3(DIM / 32, KV_TOK / 32), 256, 0, stream>>>(
      KVb + DIM, VT, KV_TOK, DIM, 2 * DIM);           // VTd [D, KV]
  for (int h = 0; h < NHEAD; ++h) {
    __bf16* Ph = Pbd + (size_t)h * T_TOK * KV_TOK;
    ggemm_f(Qb + h * DHEAD, KVb + h * DHEAD, SD,
            T_TOK, KV_TOK, DHEAD, DIM, 2 * DIM, KV_TOK, stream);
    attn_softmax_kernel<1><<<T_TOK, 256, KV_TOK * 4, stream>>>(SD, Ph, KV_TOK, pb, pp, tb, tp);
    ggemm_b(Ph, VT + (size_t)h * DHEAD * KV_TOK, Ob + h * DHEAD,
            T_TOK, DHEAD, KV_TOK, KV_TOK, KV_TOK, DIM, stream);
  }
  ggemm_acc(Ob, wOT, Y, T_TOK, DIM, DIM, DIM, DIM, DIM, stream);       // y = xq + attn@Wo
  rms_bf16<<<T_TOK, 256, 0, stream>>>(Y, gd_ln2, XNb, nullptr);
  ggemm_b(XNb, wM1T, MHb, T_TOK, FFDIM, DIM, DIM, DIM, FFDIM, stream);
  gelu_bf16<<<(T_TOK * FFDIM / 8 + 255) / 256, 256, 0, stream>>>(MHb, (long)T_TOK * FFDIM / 8);
  ggemm_acc(MHb, wM2T, Y, T_TOK, DIM, FFDIM, FFDIM, FFDIM, DIM, stream);  // y += mlp
  rms_bf16<<<T_TOK, 256, 0, stream>>>(Y, gd_lnf, XNb, nullptr);
  conv_bf16<<<((long)VOCAB * DIM / 8 + 255) / 256, 256, 0, stream>>>(Wd_embed, embB, (long)VOCAB * DIM / 8);
  ggemm_f(XNb, embB, DLOG, T_TOK, VOCAB, DIM, DIM, DIM, VOCAB, stream);

  // ---------------- KD loss ----------------
  kl_loss_kernel<<<T_TOK, 256, 0, stream>>>(DLOG, PT, ENT, S1, labels, nitems, (float*)d_out);
}

// Round 3
// 3286.758 us; speedup vs baseline: 4.0128x; 1.8510x over previous
//
#include <hip/hip_runtime.h>
#include <math.h>

#define P_TOK 4096
#define T_TOK 1024
#define KV_TOK 5120
#define DIM 2048
#define VOCAB 32000
#define NHEAD 8
#define DHEAD 256
#define FFDIM 8192
#define NLAYER 2

using f32x4  = __attribute__((ext_vector_type(4))) float;
using bf16x4 = __attribute__((ext_vector_type(4))) __bf16;
using bf16x8 = __attribute__((ext_vector_type(8))) __bf16;

typedef const __attribute__((address_space(1))) void* gp1_t;
typedef __attribute__((address_space(3))) void* lp3_t;

__device__ __forceinline__ void gload16(const void* g, void* l) {
  __builtin_amdgcn_global_load_lds((gp1_t)g, (lp3_t)l, 16, 0, 0);
}

__device__ __forceinline__ unsigned pack_bf2(float a, float b) {
  union { __bf16 h[2]; unsigned u; } x;
  x.h[0] = (__bf16)a; x.h[1] = (__bf16)b; return x.u;
}

// ---------------------------------------------------------------------------
// GEMM (m97 structure): C[M,N] = A[M,K] @ B^T, A bf16 [M,K] lda, B bf16 [N,K] ldb.
// ---------------------------------------------------------------------------
template<typename CT, bool ACCUM>
__global__ __launch_bounds__(256) void gemm_bt(
    const __bf16* __restrict__ A, const __bf16* __restrict__ B, CT* __restrict__ C,
    int M, int N, int K, int lda, int ldb, int ldc)
{
  __shared__ __align__(16) __bf16 As[128][64];
  __shared__ __align__(16) __bf16 Bs[128][64];
  const int tid = threadIdx.x;
  const int lane = tid & 63, wave = tid >> 6;
  const int bm = blockIdx.y << 7, bn = blockIdx.x << 7;
  const int fr = lane & 15, fq = lane >> 4;
  const int wm = (wave >> 1) << 6, wn = (wave & 1) << 6;
  const int l8 = lane >> 3;
  const int c8 = (lane & 7) << 3;
  f32x4 acc[4][4] = {};

  for (int k0 = 0; k0 < K; k0 += 64) {
#pragma unroll
    for (int i = 0; i < 4; ++i) {
      const int c = (wave << 2) + i;
      const int row = (c << 3) + l8;
      gload16(A + (size_t)(bm + row) * lda + k0 + c8, (char*)(&As[0][0]) + (c << 10));
      gload16(B + (size_t)(bn + row) * ldb + k0 + c8, (char*)(&Bs[0][0]) + (c << 10));
    }
    __syncthreads();
#pragma unroll
    for (int ks = 0; ks < 2; ++ks) {
      bf16x8 a[4], b[4];
#pragma unroll
      for (int i = 0; i < 4; ++i) {
        a[i] = *reinterpret_cast<const bf16x8*>(&As[wm + (i << 4) + fr][(ks << 5) + (fq << 3)]);
        b[i] = *reinterpret_cast<const bf16x8*>(&Bs[wn + (i << 4) + fr][(ks << 5) + (fq << 3)]);
      }
#pragma unroll
      for (int mi = 0; mi < 4; ++mi)
#pragma unroll
        for (int ni = 0; ni < 4; ++ni)
          acc[mi][ni] = __builtin_amdgcn_mfma_f32_16x16x32_bf16(a[mi], b[ni], acc[mi][ni], 0, 0, 0);
    }
    __syncthreads();
  }
#pragma unroll
  for (int mi = 0; mi < 4; ++mi) {
#pragma unroll
    for (int r = 0; r < 4; ++r) {
      const size_t rowi = (size_t)(bm + wm + (mi << 4) + (fq << 2) + r);
      CT* Crow = C + rowi * ldc + bn + wn + fr;
#pragma unroll
      for (int ni = 0; ni < 4; ++ni) {
        if (ACCUM) Crow[ni << 4] += (CT)acc[mi][ni][r];
        else       Crow[ni << 4] = (CT)acc[mi][ni][r];
      }
    }
  }
}

// ---------------------------------------------------------------------------
// Fused flash attention with block-sparse tile skipping.
// Grid: (nq/64, NHEAD). 4 waves; wave owns 16 q rows. KVBLK=64, DHEAD=256.
// MODE 0 (target): vis = pb[k]==pb[q] && pp[q]>=pp[k]
// MODE 1 (draft):  k<P: pb[k]==tb[q] && anchor(q)>pp[k];  k>=P: tb[kk]==tb[q] && kk/16==q/16
// ---------------------------------------------------------------------------
template<int MODE>
__global__ __launch_bounds__(256, 2) void flash_attn(
    const __bf16* __restrict__ Q, int ldq,
    const __bf16* __restrict__ K, int ldk,
    const __bf16* __restrict__ VT, int lenKV,
    __bf16* __restrict__ Oout, int ldo,
    const int* __restrict__ pb, const int* __restrict__ pp,
    const int* __restrict__ tb, const int* __restrict__ tp)
{
  __shared__ __align__(16) char KsB[64 * 512];    // K tile  [64 kv][256 d] bf16, swizzled
  __shared__ __align__(16) char VtsB[256 * 128];  // V^T tile [256 d][64 kv] bf16, swizzled
  __shared__ __align__(16) char PsB[64 * 128];    // P tile  [64 q][64 kv] bf16, swizzled
  const int tid = threadIdx.x;
  const int lane = tid & 63, wave = tid >> 6;
  const int fr = lane & 15, fq = lane >> 4;
  const int sw7 = fr & 7;
  const int q0 = blockIdx.x << 6;
  const int h = blockIdx.y;
  const __bf16* Qh = Q + (size_t)h * DHEAD;
  const __bf16* Kh = K + (size_t)h * DHEAD;
  const __bf16* VTh = VT + (size_t)h * DHEAD * lenKV;

  // block-level q stats (identical in all waves)
  int qb_l, aux_l;
  if (MODE == 0) { qb_l = pb[q0 + lane]; aux_l = pp[q0 + lane]; }
  else           { qb_l = tb[q0 + lane]; aux_l = tp[((q0 + lane) >> 4) << 4]; }
  const int qb0 = __shfl(qb_l, 0);
  const bool uniform = __all(qb_l == qb0);
  int amax = aux_l;
#pragma unroll
  for (int s = 1; s < 64; s <<= 1) amax = max(amax, __shfl_xor(amax, s));

  // per-lane q row (lane's softmax column): q = q0 + wave*16 + fr
  const int q_s = q0 + (wave << 4) + fr;
  int qb_s, aux_s;
  if (MODE == 0) { qb_s = pb[q_s]; aux_s = pp[q_s]; }
  else           { qb_s = tb[q_s]; aux_s = tp[(q_s >> 4) << 4]; }
  const int qblk_s = q_s >> 4;

  // Q fragments in registers (B-operand layout), reused across all KV tiles
  bf16x8 qreg[8];
#pragma unroll
  for (int ds = 0; ds < 8; ++ds)
    qreg[ds] = *reinterpret_cast<const bf16x8*>(
        Qh + (size_t)q_s * ldq + (ds << 5) + (fq << 3));

  f32x4 acc[16] = {};
  float mrun = -1.0e30f, lrun = 0.0f;

  for (int kv0 = 0; kv0 < lenKV; kv0 += 64) {
    // ---- exact-conservative tile skip ----
    bool ok;
    if (MODE == 0) {
      ok = (pb[kv0 + lane] == qb0) && (pp[kv0 + lane] <= amax);
    } else if (kv0 < P_TOK) {
      ok = (pb[kv0 + lane] == qb0) && (pp[kv0 + lane] < amax);
    } else {
      const int kk = kv0 - P_TOK + lane;
      const int kb = kk >> 4;
      ok = (tb[kk] == qb0) && (kb >= (q0 >> 4)) && (kb <= ((q0 + 63) >> 4));
    }
    if (uniform && !__any(ok)) continue;

    __syncthreads();   // all waves done reading previous tile's Ks/Vts
    // ---- stage K + V^T (linear LDS dest, inverse-swizzled global source) ----
#pragma unroll
    for (int i = 0; i < 8; ++i) {
      const int s = wave + (i << 2);
      const int cl = (s << 6) + lane;
      {
        const int r = cl >> 5, c = cl & 31;
        gload16(Kh + (size_t)(kv0 + r) * ldk + ((c ^ (r & 7)) << 3), KsB + (s << 10));
      }
      {
        const int rd = cl >> 3, c = cl & 7;
        gload16(VTh + (size_t)rd * lenKV + kv0 + ((c ^ (rd & 7)) << 3), VtsB + (s << 10));
      }
    }
    __syncthreads();   // staged (compiler drains vmcnt before barrier)

    // ---- swapped QK^T: S^T[k][q] = mfma(K, Q) ----
    f32x4 st[4] = {};
#pragma unroll
    for (int ds = 0; ds < 8; ++ds) {
#pragma unroll
      for (int mt = 0; mt < 4; ++mt) {
        const bf16x8 kf = *reinterpret_cast<const bf16x8*>(
            KsB + ((mt << 4) + fr) * 512 + ((((ds << 2) + fq) ^ sw7) << 4));
        st[mt] = __builtin_amdgcn_mfma_f32_16x16x32_bf16(kf, qreg[ds], st[mt], 0, 0, 0);
      }
    }

    // ---- mask + scale: lane holds P[q=q_s][k = kv0+mt*16+4fq+r] ----
    float pv[16];
    float tmax = -3.0e38f;
#pragma unroll
    for (int mt = 0; mt < 4; ++mt) {
      const int kbase = kv0 + (mt << 4) + (fq << 2);
      bool vis[4];
      if (MODE == 0) {
        const int4 pbv = *reinterpret_cast<const int4*>(pb + kbase);
        const int4 ppv = *reinterpret_cast<const int4*>(pp + kbase);
        vis[0] = (pbv.x == qb_s) && (aux_s >= ppv.x);
        vis[1] = (pbv.y == qb_s) && (aux_s >= ppv.y);
        vis[2] = (pbv.z == qb_s) && (aux_s >= ppv.z);
        vis[3] = (pbv.w == qb_s) && (aux_s >= ppv.w);
      } else if (kv0 < P_TOK) {
        const int4 pbv = *reinterpret_cast<const int4*>(pb + kbase);
        const int4 ppv = *reinterpret_cast<const int4*>(pp + kbase);
        vis[0] = (pbv.x == qb_s) && (aux_s > ppv.x);
        vis[1] = (pbv.y == qb_s) && (aux_s > ppv.y);
        vis[2] = (pbv.z == qb_s) && (aux_s > ppv.z);
        vis[3] = (pbv.w == qb_s) && (aux_s > ppv.w);
      } else {
        const int4 tbv = *reinterpret_cast<const int4*>(tb + kbase - P_TOK);
        const bool blkok = (((kv0 - P_TOK) >> 4) + mt) == qblk_s;
        vis[0] = (tbv.x == qb_s) && blkok;
        vis[1] = (tbv.y == qb_s) && blkok;
        vis[2] = (tbv.z == qb_s) && blkok;
        vis[3] = (tbv.w == qb_s) && blkok;
      }
#pragma unroll
      for (int r = 0; r < 4; ++r) {
        const float sv = st[mt][r] * 0.0625f;
        const float val = vis[r] ? sv : -1.0e30f;
        pv[(mt << 2) + r] = val;
        tmax = fmaxf(tmax, val);
      }
    }
    tmax = fmaxf(tmax, __shfl_xor(tmax, 16));
    tmax = fmaxf(tmax, __shfl_xor(tmax, 32));

    // ---- online softmax with defer-max (T13, thr=8) ----
    const float m_old = mrun;
    const bool grow = tmax > m_old + 8.0f;
    const float mnew = grow ? tmax : m_old;
    float tsum = 0.f;
#pragma unroll
    for (int i = 0; i < 16; ++i) { pv[i] = __expf(pv[i] - mnew); tsum += pv[i]; }
    tsum += __shfl_xor(tsum, 16);
    tsum += __shfl_xor(tsum, 32);
    const float fac = __expf(m_old - mnew);
    lrun = lrun * fac + tsum;
    mrun = mnew;

    // ---- write P tile to LDS (per-wave 16 rows, swizzled) ----
#pragma unroll
    for (int mt = 0; mt < 4; ++mt) {
#pragma unroll
      for (int rp = 0; rp < 4; rp += 2) {
        const unsigned u = pack_bf2(pv[(mt << 2) + rp], pv[(mt << 2) + rp + 1]);
        *reinterpret_cast<unsigned*>(PsB + ((wave << 4) + fr) * 128
            + ((((mt << 1) + (fq >> 1)) ^ sw7) << 4) + ((fq & 1) << 3) + ((rp >> 1) << 2)) = u;
      }
    }

    // ---- rescale O accumulator (skipped when no row grew) ----
    if (!__all(!grow)) {
#pragma unroll
      for (int r = 0; r < 4; ++r) {
        const float f_r = __shfl(fac, ((lane >> 4) << 2) + r);
#pragma unroll
        for (int dt = 0; dt < 16; ++dt) acc[dt][r] *= f_r;
      }
    }

    // ---- PV: acc[q][d] += P @ V ----
#pragma unroll
    for (int kk = 0; kk < 2; ++kk) {
      const bf16x8 pa = *reinterpret_cast<const bf16x8*>(
          PsB + ((wave << 4) + fr) * 128 + ((((kk << 2) + fq) ^ sw7) << 4));
#pragma unroll
      for (int dt = 0; dt < 16; ++dt) {
        const bf16x8 vb = *reinterpret_cast<const bf16x8*>(
            VtsB + ((dt << 4) + fr) * 128 + ((((kk << 2) + fq) ^ sw7) << 4));
        acc[dt] = __builtin_amdgcn_mfma_f32_16x16x32_bf16(pa, vb, acc[dt], 0, 0, 0);
      }
    }
  }

  // ---- epilogue: O /= l, store bf16 ----
#pragma unroll
  for (int r = 0; r < 4; ++r) {
    const float linv = 1.0f / __shfl(lrun, ((lane >> 4) << 2) + r);
    const int rowg = q0 + (wave << 4) + (fq << 2) + r;
#pragma unroll
    for (int dt = 0; dt < 16; ++dt)
      Oout[(size_t)rowg * ldo + (size_t)h * DHEAD + (dt << 4) + fr] = (__bf16)(acc[dt][r] * linv);
  }
}

// ---------------------------------------------------------------------------
// fp32 [R,C] (ld) -> bf16 [C,R] transpose-convert
// ---------------------------------------------------------------------------
__global__ __launch_bounds__(256) void transpose_f2b(const float* __restrict__ src,
    __bf16* __restrict__ dst, int R, int C, int ld)
{
  __shared__ float tile[32][33];
  const int bx = blockIdx.x << 5, by = blockIdx.y << 5;
  const int tx = threadIdx.x & 31, ty = threadIdx.x >> 5;
#pragma unroll
  for (int k = 0; k < 32; k += 8)
    tile[ty + k][tx] = src[(size_t)(by + ty + k) * ld + bx + tx];
  __syncthreads();
#pragma unroll
  for (int k = 0; k < 32; k += 8)
    dst[(size_t)(bx + ty + k) * R + by + tx] = (__bf16)tile[tx][ty + k];
}

__global__ __launch_bounds__(256) void transpose_b2b(const __bf16* __restrict__ src,
    __bf16* __restrict__ dst, int R, int C, int ld)
{
  __shared__ __bf16 tile[32][33];
  const int bx = blockIdx.x << 5, by = blockIdx.y << 5;
  const int tx = threadIdx.x & 31, ty = threadIdx.x >> 5;
#pragma unroll
  for (int k = 0; k < 32; k += 8)
    tile[ty + k][tx] = src[(size_t)(by + ty + k) * ld + bx + tx];
  __syncthreads();
#pragma unroll
  for (int k = 0; k < 32; k += 8)
    dst[(size_t)(bx + ty + k) * R + by + tx] = tile[tx][ty + k];
}

__global__ __launch_bounds__(256) void conv_bf16(const float* __restrict__ src,
    __bf16* __restrict__ dst, long n8)
{
  const long i = (long)blockIdx.x * 256 + threadIdx.x;
  if (i >= n8) return;
  const float4 a = reinterpret_cast<const float4*>(src)[i * 2];
  const float4 b = reinterpret_cast<const float4*>(src)[i * 2 + 1];
  bf16x8 h;
  h[0] = (__bf16)a.x; h[1] = (__bf16)a.y; h[2] = (__bf16)a.z; h[3] = (__bf16)a.w;
  h[4] = (__bf16)b.x; h[5] = (__bf16)b.y; h[6] = (__bf16)b.z; h[7] = (__bf16)b.w;
  reinterpret_cast<bf16x8*>(dst)[i] = h;
}

__global__ __launch_bounds__(256) void rms_bf16(const float* __restrict__ x,
    const float* __restrict__ g, __bf16* __restrict__ y, const int* __restrict__ row_idx)
{
  __shared__ float red[256];
  const int r = blockIdx.x;
  const int src = row_idx ? row_idx[r] : r;
  const float* xr = x + (size_t)src * DIM;
  __bf16* yr = y + (size_t)r * DIM;
  const int t = threadIdx.x;
  const float4 v0 = *reinterpret_cast<const float4*>(xr + t * 8);
  const float4 v1 = *reinterpret_cast<const float4*>(xr + t * 8 + 4);
  float ss = v0.x * v0.x + v0.y * v0.y + v0.z * v0.z + v0.w * v0.w
           + v1.x * v1.x + v1.y * v1.y + v1.z * v1.z + v1.w * v1.w;
  red[t] = ss; __syncthreads();
  for (int s = 128; s > 0; s >>= 1) { if (t < s) red[t] += red[t + s]; __syncthreads(); }
  const float inv = rsqrtf(red[0] * (1.0f / DIM) + 1e-6f);
  const float4 g0 = *reinterpret_cast<const float4*>(g + t * 8);
  const float4 g1 = *reinterpret_cast<const float4*>(g + t * 8 + 4);
  bf16x8 h;
  h[0] = (__bf16)(v0.x * g0.x * inv); h[1] = (__bf16)(v0.y * g0.y * inv);
  h[2] = (__bf16)(v0.z * g0.z * inv); h[3] = (__bf16)(v0.w * g0.w * inv);
  h[4] = (__bf16)(v1.x * g1.x * inv); h[5] = (__bf16)(v1.y * g1.y * inv);
  h[6] = (__bf16)(v1.z * g1.z * inv); h[7] = (__bf16)(v1.w * g1.w * inv);
  *reinterpret_cast<bf16x8*>(yr + t * 8) = h;
}

__global__ __launch_bounds__(256) void gather_rows_kernel(const float* __restrict__ tab,
    const int* __restrict__ ids, float* __restrict__ out)
{
  const int r = blockIdx.x;
  const float* src = tab + (size_t)ids[r] * DIM;
  float* dst = out + (size_t)r * DIM;
  const int t = threadIdx.x;
  *reinterpret_cast<float4*>(dst + t * 8) = *reinterpret_cast<const float4*>(src + t * 8);
  *reinterpret_cast<float4*>(dst + t * 8 + 4) = *reinterpret_cast<const float4*>(src + t * 8 + 4);
}

__device__ __forceinline__ float gelu_tanh(float u) {
  const float c = 0.7978845608028654f * (u + 0.044715f * u * u * u);
  return 0.5f * u * (1.0f + tanhf(c));
}

__global__ __launch_bounds__(256) void gelu_bf16(__bf16* __restrict__ x, long n8)
{
  const long i = (long)blockIdx.x * 256 + threadIdx.x;
  if (i >= n8) return;
  bf16x8 v = reinterpret_cast<bf16x8*>(x)[i];
#pragma unroll
  for (int j = 0; j < 8; ++j) v[j] = (__bf16)gelu_tanh((float)v[j]);
  reinterpret_cast<bf16x8*>(x)[i] = v;
}

// ---------------------------------------------------------------------------
// Teacher softmax: logits fp32 [T,V] -> PT bf16, ENT[r]=sum pt*lpt, S1[r]=sum pt
// ---------------------------------------------------------------------------
__global__ __launch_bounds__(256) void teacher_softmax_kernel(const float* __restrict__ TL,
    __bf16* __restrict__ PT, float* __restrict__ ENT, float* __restrict__ S1)
{
  __shared__ float sm[256], ss[256];
  const int r = blockIdx.x, t = threadIdx.x;
  const float* tl = TL + (size_t)r * VOCAB;
  __bf16* pt = PT + (size_t)r * VOCAB;
  float m = -3.0e38f, s = 0.f;
  for (int v = t; v < VOCAB; v += 256) {
    const float x = tl[v];
    if (x > m) { s = s * expf(m - x) + 1.f; m = x; }
    else       { s += expf(x - m); }
  }
  sm[t] = m; ss[t] = s; __syncthreads();
  for (int st = 128; st > 0; st >>= 1) {
    if (t < st) {
      const float m2 = sm[t + st], s2 = ss[t + st];
      const float M = fmaxf(sm[t], m2);
      ss[t] = ss[t] * expf(sm[t] - M) + s2 * expf(m2 - M);
      sm[t] = M;
    }
    __syncthreads();
  }
  const float Mt = sm[0], Z = ss[0];
  const float invZ = 1.0f / Z, lZ = logf(Z);
  __syncthreads();
  float ent = 0.f, s1 = 0.f;
  for (int v = t; v < VOCAB; v += 256) {
    const float x = tl[v];
    const float p = expf(x - Mt) * invZ;
    const __bf16 pb_ = (__bf16)p;
    pt[v] = pb_;
    const float pf = (float)pb_;
    ent += pf * (x - Mt - lZ);
    s1 += pf;
  }
  sm[t] = ent; ss[t] = s1; __syncthreads();
  for (int st = 128; st > 0; st >>= 1) {
    if (t < st) { sm[t] += sm[t + st]; ss[t] += ss[t + st]; }
    __syncthreads();
  }
  if (t == 0) { ENT[r] = sm[0]; S1[r] = ss[0]; }
}

__global__ __launch_bounds__(256) void kl_loss_kernel(const float* __restrict__ DL,
    const __bf16* __restrict__ PT, const float* __restrict__ ENT, const float* __restrict__ S1,
    const int* __restrict__ labels, const int* __restrict__ nitems, float* __restrict__ out)
{
  __shared__ float sm[256], ss[256];
  const int r = blockIdx.x, t = threadIdx.x;
  if (labels[r] == -100) return;
  const float* dl = DL + (size_t)r * VOCAB;
  const __bf16* pt = PT + (size_t)r * VOCAB;
  float m = -3.0e38f, s = 0.f;
  for (int v = t; v < VOCAB; v += 256) {
    const float x = dl[v];
    if (x > m) { s = s * expf(m - x) + 1.f; m = x; }
    else       { s += expf(x - m); }
  }
  sm[t] = m; ss[t] = s; __syncthreads();
  for (int st = 128; st > 0; st >>= 1) {
    if (t < st) {
      const float m2 = sm[t + st], s2 = ss[t + st];
      const float M = fmaxf(sm[t], m2);
      ss[t] = ss[t] * expf(sm[t] - M) + s2 * expf(m2 - M);
      sm[t] = M;
    }
    __syncthreads();
  }
  const float lses = sm[0] + logf(ss[0]);
  __syncthreads();
  float cross = 0.f;
  for (int v = t; v < VOCAB; v += 256) cross += (float)pt[v] * dl[v];
  ss[t] = cross; __syncthreads();
  for (int st = 128; st > 0; st >>= 1) { if (t < st) ss[t] += ss[t + st]; __syncthreads(); }
  if (t == 0) {
    const int raw = nitems[0];
    const float n = (raw > 0 && raw < 1000000) ? (float)raw : __int_as_float(raw);
    const float loss_r = ENT[r] - ss[0] + lses * S1[r];
    atomicAdd(out, loss_r / n);
  }
}

// ---------------------------------------------------------------------------
static inline void ggemm_b(const __bf16* A, const __bf16* B, __bf16* C,
                           int M, int N, int K, int lda, int ldb, int ldc, hipStream_t s)
{ gemm_bt<__bf16, false><<<dim3(N / 128, M / 128), 256, 0, s>>>(A, B, C, M, N, K, lda, ldb, ldc); }
static inline void ggemm_f(const __bf16* A, const __bf16* B, float* C,
                           int M, int N, int K, int lda, int ldb, int ldc, hipStream_t s)
{ gemm_bt<float, false><<<dim3(N / 128, M / 128), 256, 0, s>>>(A, B, C, M, N, K, lda, ldb, ldc); }
static inline void ggemm_acc(const __bf16* A, const __bf16* B, float* C,
                             int M, int N, int K, int lda, int ldb, int ldc, hipStream_t s)
{ gemm_bt<float, true><<<dim3(N / 128, M / 128), 256, 0, s>>>(A, B, C, M, N, K, lda, ldb, ldc); }

extern "C" void kernel_launch(void* const* d_in, const int* in_sizes, int n_in,
                              void* d_out, int out_size, void* d_ws, size_t ws_size,
                              hipStream_t stream)
{
  const int* prefix_ids = (const int*)d_in[0];
  const int* pb        = (const int*)d_in[1];
  const int* pp        = (const int*)d_in[2];
  const int* input_ids = (const int*)d_in[3];
  const int* tb        = (const int*)d_in[4];
  const int* tp        = (const int*)d_in[5];
  const int* tgi       = (const int*)d_in[6];
  const int* labels    = (const int*)d_in[7];
  const int* nitems    = (const int*)d_in[8];
  const float* Wt_embed = (const float*)d_in[9];
  const float* Wt_qkv   = (const float*)d_in[10];
  const float* Wt_o     = (const float*)d_in[11];
  const float* Wt_m1    = (const float*)d_in[12];
  const float* Wt_m2    = (const float*)d_in[13];
  const float* gt_ln1   = (const float*)d_in[14];
  const float* gt_ln2   = (const float*)d_in[15];
  const float* gt_lnf   = (const float*)d_in[16];
  const float* Wd_embed = (const float*)d_in[17];
  const float* Wd_qkv   = (const float*)d_in[18];
  const float* Wd_o     = (const float*)d_in[19];
  const float* Wd_m1    = (const float*)d_in[20];
  const float* Wd_m2    = (const float*)d_in[21];
  const float* gd_ln1   = (const float*)d_in[22];
  const float* gd_ln2   = (const float*)d_in[23];
  const float* gd_lnf   = (const float*)d_in[24];

  // ---------------- workspace layout (bytes) ----------------
  char* base = (char*)d_ws;
  size_t off = 0;
  auto alloc = [&](size_t bytes) { size_t o = off; off += (bytes + 255) & ~(size_t)255; return o; };
  const size_t oX    = alloc((size_t)P_TOK * DIM * 4);       // fp32 residual / hidden
  const size_t oXNb  = alloc((size_t)KV_TOK * DIM * 2);      // bf16 normed activations
  const size_t oQKVb = alloc((size_t)P_TOK * 3 * DIM * 2);   // 48MB \  contiguous group:
  const size_t oOb   = alloc((size_t)P_TOK * DIM * 2);       // 16MB  | TLOG/DLOG fp32 [T,V]
  const size_t oVT   = alloc((size_t)DIM * KV_TOK * 2);      // 20MB  | (125MB) overlays it
  const size_t oMHb  = alloc((size_t)P_TOK * FFDIM * 2);     // 64MB /
  const size_t oY    = alloc((size_t)T_TOK * DIM * 4);       // fp32 draft residual
  const size_t oPT   = alloc((size_t)T_TOK * VOCAB * 2);     // bf16 teacher probs
  const size_t oENT  = alloc((size_t)T_TOK * 4);
  const size_t oS1   = alloc((size_t)T_TOK * 4);
  const size_t oEMB  = alloc((size_t)VOCAB * DIM * 2);       // bf16 embed table
  const size_t oWB   = alloc((size_t)(3 * DIM * DIM + DIM * DIM + DIM * FFDIM + FFDIM * DIM) * 2);
  if (ws_size < off) return;  // fail loudly (d_out stays poisoned)

  float*  X    = (float*)(base + oX);
  __bf16* XNb  = (__bf16*)(base + oXNb);
  __bf16* QKVb = (__bf16*)(base + oQKVb);
  __bf16* Ob   = (__bf16*)(base + oOb);
  __bf16* VT   = (__bf16*)(base + oVT);
  __bf16* MHb  = (__bf16*)(base + oMHb);
  float*  Y    = (float*)(base + oY);
  __bf16* PT   = (__bf16*)(base + oPT);
  float*  ENT  = (float*)(base + oENT);
  float*  S1   = (float*)(base + oS1);
  __bf16* embB = (__bf16*)(base + oEMB);
  __bf16* wQkvT = (__bf16*)(base + oWB);                       // [3D, D]
  __bf16* wOT   = wQkvT + (size_t)3 * DIM * DIM;               // [D, D]
  __bf16* wM1T  = wOT + (size_t)DIM * DIM;                     // [FF, D]
  __bf16* wM2T  = wM1T + (size_t)FFDIM * DIM;                  // [D, FF]
  // logits overlay: QKVb..MHb (148MB contiguous) is dead when logits are computed
  float*  TLOG = (float*)(base + oQKVb);
  float*  DLOG = (float*)(base + oQKVb);

  hipMemsetAsync(d_out, 0, sizeof(float), stream);

  // ---------------- target causal prefill ----------------
  gather_rows_kernel<<<P_TOK, 256, 0, stream>>>(Wt_embed, prefix_ids, X);
  for (int l = 0; l < NLAYER; ++l) {
    transpose_f2b<<<dim3(3 * DIM / 32, DIM / 32), 256, 0, stream>>>(
        Wt_qkv + (size_t)l * DIM * 3 * DIM, wQkvT, DIM, 3 * DIM, 3 * DIM);
    transpose_f2b<<<dim3(DIM / 32, DIM / 32), 256, 0, stream>>>(
        Wt_o + (size_t)l * DIM * DIM, wOT, DIM, DIM, DIM);
    transpose_f2b<<<dim3(FFDIM / 32, DIM / 32), 256, 0, stream>>>(
        Wt_m1 + (size_t)l * DIM * FFDIM, wM1T, DIM, FFDIM, FFDIM);
    transpose_f2b<<<dim3(DIM / 32, FFDIM / 32), 256, 0, stream>>>(
        Wt_m2 + (size_t)l * FFDIM * DIM, wM2T, FFDIM, DIM, DIM);

    rms_bf16<<<P_TOK, 256, 0, stream>>>(X, gt_ln1 + l * DIM, XNb, nullptr);
    ggemm_b(XNb, wQkvT, QKVb, P_TOK, 3 * DIM, DIM, DIM, DIM, 3 * DIM, stream);
    transpose_b2b<<<dim3(DIM / 32, P_TOK / 32), 256, 0, stream>>>(
        QKVb + 2 * DIM, VT, P_TOK, DIM, 3 * DIM);                 // VT [D,P]
    flash_attn<0><<<dim3(P_TOK / 64, NHEAD), 256, 0, stream>>>(
        QKVb, 3 * DIM, QKVb + DIM, 3 * DIM, VT, P_TOK, Ob, DIM, pb, pp, nullptr, nullptr);
    ggemm_acc(Ob, wOT, X, P_TOK, DIM, DIM, DIM, DIM, DIM, stream);   // X += attn@Wo
    rms_bf16<<<P_TOK, 256, 0, stream>>>(X, gt_ln2 + l * DIM, XNb, nullptr);
    ggemm_b(XNb, wM1T, MHb, P_TOK, FFDIM, DIM, DIM, DIM, FFDIM, stream);
    gelu_bf16<<<(P_TOK * FFDIM / 8 + 255) / 256, 256, 0, stream>>>(MHb, (long)P_TOK * FFDIM / 8);
    ggemm_acc(MHb, wM2T, X, P_TOK, DIM, FFDIM, FFDIM, FFDIM, DIM, stream);  // X += mlp
  }

  // ---------------- teacher logits -> PT/ENT/S1 ----------------
  rms_bf16<<<T_TOK, 256, 0, stream>>>(X, gt_lnf, XNb, tgi);
  conv_bf16<<<((long)VOCAB * DIM / 8 + 255) / 256, 256, 0, stream>>>(Wt_embed, embB, (long)VOCAB * DIM / 8);
  ggemm_f(XNb, embB, TLOG, T_TOK, VOCAB, DIM, DIM, DIM, VOCAB, stream);
  teacher_softmax_kernel<<<T_TOK, 256, 0, stream>>>(TLOG, PT, ENT, S1);

  // ---------------- draft forward ----------------
  gather_rows_kernel<<<T_TOK, 256, 0, stream>>>(Wd_embed, input_ids, Y);   // Y = xq (fp32)
  transpose_f2b<<<dim3(3 * DIM / 32, DIM / 32), 256, 0, stream>>>(Wd_qkv, wQkvT, DIM, 3 * DIM, 3 * DIM);
  transpose_f2b<<<dim3(DIM / 32, DIM / 32), 256, 0, stream>>>(Wd_o, wOT, DIM, DIM, DIM);
  transpose_f2b<<<dim3(FFDIM / 32, DIM / 32), 256, 0, stream>>>(Wd_m1, wM1T, DIM, FFDIM, FFDIM);
  transpose_f2b<<<dim3(DIM / 32, FFDIM / 32), 256, 0, stream>>>(Wd_m2, wM2T, FFDIM, DIM, DIM);

  rms_bf16<<<P_TOK, 256, 0, stream>>>(X, gd_ln1, XNb, nullptr);                       // xkv_n[0:P]
  rms_bf16<<<T_TOK, 256, 0, stream>>>(Y, gd_ln1, XNb + (size_t)P_TOK * DIM, nullptr); // xq_n
  __bf16* Qb  = QKVb;                                  // [T, D]
  __bf16* KVb = QKVb + (size_t)T_TOK * DIM;            // [KV, 2D] (k | v)
  ggemm_b(XNb + (size_t)P_TOK * DIM, wQkvT, Qb, T_TOK, DIM, DIM, DIM, DIM, DIM, stream);
  ggemm_b(XNb, wQkvT + (size_t)DIM * DIM, KVb, KV_TOK, 2 * DIM, DIM, DIM, DIM, 2 * DIM, stream);
  transpose_b2b<<<dim3(DIM / 32, KV_TOK / 32), 256, 0, stream>>>(
      KVb + DIM, VT, KV_TOK, DIM, 2 * DIM);           // VTd [D, KV]
  flash_attn<1><<<dim3(T_TOK / 64, NHEAD), 256, 0, stream>>>(
      Qb, DIM, KVb, 2 * DIM, VT, KV_TOK, Ob, DIM, pb, pp, tb, tp);
  ggemm_acc(Ob, wOT, Y, T_TOK, DIM, DIM, DIM, DIM, DIM, stream);       // y = xq + attn@Wo
  rms_bf16<<<T_TOK, 256, 0, stream>>>(Y, gd_ln2, XNb, nullptr);
  ggemm_b(XNb, wM1T, MHb, T_TOK, FFDIM, DIM, DIM, DIM, FFDIM, stream);
  gelu_bf16<<<(T_TOK * FFDIM / 8 + 255) / 256, 256, 0, stream>>>(MHb, (long)T_TOK * FFDIM / 8);
  ggemm_acc(MHb, wM2T, Y, T_TOK, DIM, FFDIM, FFDIM, FFDIM, DIM, stream);  // y += mlp
  rms_bf16<<<T_TOK, 256, 0, stream>>>(Y, gd_lnf, XNb, nullptr);
  conv_bf16<<<((long)VOCAB * DIM / 8 + 255) / 256, 256, 0, stream>>>(Wd_embed, embB, (long)VOCAB * DIM / 8);
  ggemm_f(XNb, embB, DLOG, T_TOK, VOCAB, DIM, DIM, DIM, VOCAB, stream);

  // ---------------- KD loss ----------------
  kl_loss_kernel<<<T_TOK, 256, 0, stream>>>(DLOG, PT, ENT, S1, labels, nitems, (float*)d_out);
}